// Round 4
// baseline (31205.392 us; speedup 1.0000x reference)
//
#include <hip/hip_runtime.h>
#include <hip/hip_bf16.h>

// Problem: BATCH=128, SEQ=1024, DIN=512, HID=512 (all fp32)
// out = final hidden state (128, 512) of h_t = tanh(x_t@Wx + h_{t-1}@Wh + b)
//
// R4 design: column-split recurrence, coalesced flag+fence exchange.
//  - 128 blocks = 32 batch-groups (4 rows) x 4 col-slices (128 cols).
//  - Wh[:, slice] lives in VGPRs (64 x v2f = 128 regs), loaded once.
//  - Exchange layout hx[buf][bb][r][k] (k contiguous): publish = coalesced
//    256B/wave plain stores; consume = broadcast float4 loads via L1.
//  - Sync: producers plain-store data -> __syncthreads (vmcnt drain) ->
//    thread0 RELEASE-store flag (wbl2); consumers RELAXED-poll flag ->
//    ACQUIRE fence (inv) -> plain loads. One flag op per block per step.
//  - Own slice is MAC'd from LDS (hOwn) with no global round-trip, giving
//    remote producers time to propagate before we poll them.

#define BATCH 128
#define SEQ   1024
#define DIN   512
#define HID   512

#define NG  32   // batch groups
#define NC  4    // col slices
#define RPB 4    // rows per block
#define CPB 128  // cols per block

#define FLAG_STRIDE 16  // one cache line per group's flags

typedef float v2f __attribute__((ext_vector_type(2)));

// ---------------------------------------------------------------------------
// Kernel 1: xp[s][b][j] = sum_d x[b][s][d] * Wx[d][j] + bias[j]   (unchanged)
// ---------------------------------------------------------------------------
__global__ __launch_bounds__(256) void xp_gemm(
    const float* __restrict__ x, const float* __restrict__ Wx,
    const float* __restrict__ bias, float* __restrict__ xp,
    int s0)
{
    __shared__ __align__(16) float As[16][64 + 4];
    __shared__ __align__(16) float Bs[16][64];

    const int tid = threadIdx.x;
    const int tx = tid & 15;
    const int ty = tid >> 4;
    const int rowBase = blockIdx.x * 64;
    const int colBase = blockIdx.y * 64;

    const int a_r  = tid >> 2;
    const int a_k4 = (tid & 3) * 4;
    const int rr   = rowBase + a_r;
    const int s    = s0 + (rr >> 7);
    const int bb   = rr & 127;
    const float* a_row = x + ((size_t)bb * SEQ + s) * DIN;

    const int b_kk = tid >> 4;
    const int b_j4 = (tid & 15) * 4;

    v2f C[4][2] = {};

    for (int k0 = 0; k0 < DIN; k0 += 16) {
        float4 av = *reinterpret_cast<const float4*>(a_row + k0 + a_k4);
        As[a_k4 + 0][a_r] = av.x;
        As[a_k4 + 1][a_r] = av.y;
        As[a_k4 + 2][a_r] = av.z;
        As[a_k4 + 3][a_r] = av.w;
        float4 bv = *reinterpret_cast<const float4*>(Wx + (size_t)(k0 + b_kk) * HID + colBase + b_j4);
        *reinterpret_cast<float4*>(&Bs[b_kk][b_j4]) = bv;
        __syncthreads();

        #pragma unroll
        for (int kk = 0; kk < 16; ++kk) {
            float4 a4 = *reinterpret_cast<const float4*>(&As[kk][ty * 4]);
            float4 b4 = *reinterpret_cast<const float4*>(&Bs[kk][tx * 4]);
            v2f b01 = {b4.x, b4.y};
            v2f b23 = {b4.z, b4.w};
            float a[4] = {a4.x, a4.y, a4.z, a4.w};
            #pragma unroll
            for (int i = 0; i < 4; ++i) {
                C[i][0] += b01 * a[i];
                C[i][1] += b23 * a[i];
            }
        }
        __syncthreads();
    }

    float4 bias4 = *reinterpret_cast<const float4*>(bias + colBase + tx * 4);
    #pragma unroll
    for (int i = 0; i < 4; ++i) {
        int orow = rowBase + ty * 4 + i;
        float4 o;
        o.x = C[i][0].x + bias4.x;
        o.y = C[i][0].y + bias4.y;
        o.z = C[i][1].x + bias4.z;
        o.w = C[i][1].y + bias4.w;
        *reinterpret_cast<float4*>(xp + (size_t)orow * HID + colBase + tx * 4) = o;
    }
}

// ---------------------------------------------------------------------------
// Zero flags (NG*FLAG_STRIDE words) + hx buffer 0 (NG*RPB*HID floats),
// contiguous at the start of ws. Re-run every call (ws is re-poisoned).
// ---------------------------------------------------------------------------
#define INIT_WORDS (NG * FLAG_STRIDE + NG * RPB * HID)   // 512 + 65536

__global__ void init_ws(unsigned int* ws)
{
    int idx = blockIdx.x * blockDim.x + threadIdx.x;
    if (idx < INIT_WORDS) ws[idx] = 0u;
}

// ---------------------------------------------------------------------------
// Kernel 2: recurrence.
//   Block (cb, bb): rows [4bb, 4bb+4), cols [128cb, 128cb+128).
//   blockIdx = cb*NG + bb  -> group members congruent mod 8 (XCD heuristic).
//
//   MAC mapping:    tid = kq*64 + c2  (kq in [0,8): 16 k per slice; c2: col pair)
//   Reduce mapping: tid = rr*128 + cc
//
//   w2[i*16+kk] holds Wh[128*sl + 16*kq + kk][128*cb + 2*c2 .. +1] for
//   sl = (cb+i)&3  -- processing order, so all w2 indices are compile-time.
// ---------------------------------------------------------------------------
__global__ __launch_bounds__(512, 2) void recur_kernel(
    const float* __restrict__ xp,       // chunk base: xp[s-s0][b][j]
    const float* __restrict__ Wh,
    float* __restrict__ out,
    unsigned int* __restrict__ flags,   // [NG][FLAG_STRIDE]
    float* __restrict__ hx,             // [2][NG][RPB][HID]
    int s0, int steps)
{
    const int bb = blockIdx.x & (NG - 1);
    const int cb = blockIdx.x >> 5;

    const int tid = threadIdx.x;
    const int c2 = tid & 63;     // col pair within slice
    const int kq = tid >> 6;     // k-chunk (16 k per slice)
    const int rr = tid >> 7;     // reduce: row 0..3
    const int cc = tid & 127;    // reduce: col 0..127

    __shared__ __align__(16) float part[8][RPB][CPB];   // 16 KB
    __shared__ __align__(16) float hOwn[RPB][CPB];      // 2 KB

    // ---- preload Wh slice into registers (once; reused `steps` times)
    v2f w2[64];
    #pragma unroll
    for (int i = 0; i < 4; ++i) {
        const int sl = (cb + i) & 3;
        const float* wb = Wh + (size_t)(128 * sl + 16 * kq) * HID + 128 * cb + 2 * c2;
        #pragma unroll
        for (int kk = 0; kk < 16; ++kk)
            w2[i * 16 + kk] = *reinterpret_cast<const v2f*>(wb + (size_t)kk * HID);
    }

    unsigned int* myflag = &flags[bb * FLAG_STRIDE + cb];

    const int send = s0 + steps;
    for (int s = s0; s < send; ++s) {
        // prefetch xp for this step (consumed at reduce, ~1 us later)
        float xpv = xp[((size_t)(s - s0) * BATCH + (RPB * bb + rr)) * HID + CPB * cb + cc];

        v2f acc[RPB] = {};
        const float* hsrc = hx + ((size_t)(s & 1) * NG + bb) * (RPB * HID);

        #pragma unroll
        for (int i = 0; i < 4; ++i) {
            const int sl = (cb + i) & 3;
            if (i == 0 && s > s0) {
                // own slice from LDS (written by us at the end of step s-1;
                // ordered by that step's post-publish __syncthreads)
                #pragma unroll
                for (int r = 0; r < RPB; ++r) {
                    #pragma unroll
                    for (int j = 0; j < 4; ++j) {
                        float4 h4 = *reinterpret_cast<const float4*>(&hOwn[r][16 * kq + 4 * j]);
                        acc[r] += w2[4 * j + 0] * h4.x;
                        acc[r] += w2[4 * j + 1] * h4.y;
                        acc[r] += w2[4 * j + 2] * h4.z;
                        acc[r] += w2[4 * j + 3] * h4.w;
                    }
                }
            } else {
                // wait for producer sl of our group (relaxed poll; at i==0 &&
                // s==s0 it's our own flag, already >= s0 -> passes instantly)
                unsigned int* f = &flags[bb * FLAG_STRIDE + sl];
                while (__hip_atomic_load(f, __ATOMIC_RELAXED,
                                         __HIP_MEMORY_SCOPE_AGENT) < (unsigned)s) { }
                __builtin_amdgcn_fence(__ATOMIC_ACQUIRE, "agent");
                // consume slice from global: broadcast float4 loads (L1-cached)
                const float* hs = hsrc + 128 * sl + 16 * kq;
                #pragma unroll
                for (int r = 0; r < RPB; ++r) {
                    #pragma unroll
                    for (int j = 0; j < 4; ++j) {
                        float4 h4 = *reinterpret_cast<const float4*>(hs + (size_t)r * HID + 4 * j);
                        acc[r] += w2[i * 16 + 4 * j + 0] * h4.x;
                        acc[r] += w2[i * 16 + 4 * j + 1] * h4.y;
                        acc[r] += w2[i * 16 + 4 * j + 2] * h4.z;
                        acc[r] += w2[i * 16 + 4 * j + 3] * h4.w;
                    }
                }
            }
        }

        // ---- write partials, reduce across 8 kq-groups
        #pragma unroll
        for (int r = 0; r < RPB; ++r)
            *reinterpret_cast<v2f*>(&part[kq][r][2 * c2]) = acc[r];
        __syncthreads();

        float sum = xpv;
        #pragma unroll
        for (int q = 0; q < 8; ++q)
            sum += part[q][rr][cc];
        float hn = tanhf(sum);

        // ---- publish h_{s+1}: coalesced plain stores ([r][k] layout)
        float* dst = hx + ((size_t)((s + 1) & 1) * NG + bb) * (RPB * HID);
        dst[(size_t)rr * HID + 128 * cb + cc] = hn;
        hOwn[rr][cc] = hn;
        if (s == SEQ - 1)
            out[(size_t)(RPB * bb + rr) * HID + 128 * cb + cc] = hn;

        // barrier drains vmcnt (stores in L2) and orders hOwn/part for next
        // step; then one release-store (wbl2 + flag) makes the slice visible.
        __syncthreads();
        if (tid == 0)
            __hip_atomic_store(myflag, (unsigned)(s + 1),
                               __ATOMIC_RELEASE, __HIP_MEMORY_SCOPE_AGENT);
    }
}

// ---------------------------------------------------------------------------
// Fallback (ws too small): fully fused, zero workspace.
// ---------------------------------------------------------------------------
__global__ __launch_bounds__(512) void fused_kernel(
    const float* __restrict__ x, const float* __restrict__ Wx,
    const float* __restrict__ Wh, const float* __restrict__ bias,
    float* __restrict__ out)
{
    __shared__ __align__(16) float h0[HID];
    __shared__ __align__(16) float h1[HID];
    __shared__ __align__(16) float x0[DIN];
    __shared__ __align__(16) float x1[DIN];

    const int j = threadIdx.x;
    const int b0 = blockIdx.x * 2;
    const int b1 = b0 + 1;

    h0[j] = 0.0f;
    h1[j] = 0.0f;
    __syncthreads();

    const float4* h04 = reinterpret_cast<const float4*>(h0);
    const float4* h14 = reinterpret_cast<const float4*>(h1);
    const float4* x04 = reinterpret_cast<const float4*>(x0);
    const float4* x14 = reinterpret_cast<const float4*>(x1);

    for (int s = 0; s < SEQ; ++s) {
        x0[j] = x[((size_t)b0 * SEQ + s) * DIN + j];
        x1[j] = x[((size_t)b1 * SEQ + s) * DIN + j];
        __syncthreads();

        float acc0 = bias[j];
        float acc1 = bias[j];
        const float* wx = Wx + j;
        const float* wh = Wh + j;
        #pragma unroll 2
        for (int k4 = 0; k4 < HID / 4; ++k4) {
            float4 hv0 = h04[k4];
            float4 hv1 = h14[k4];
            float4 xv0 = x04[k4];
            float4 xv1 = x14[k4];
            int k = k4 * 4;
            #pragma unroll
            for (int u = 0; u < 4; ++u) {
                float wxv = wx[(size_t)(k + u) * HID];
                float whv = wh[(size_t)(k + u) * HID];
                float he0 = (u == 0) ? hv0.x : (u == 1) ? hv0.y : (u == 2) ? hv0.z : hv0.w;
                float he1 = (u == 0) ? hv1.x : (u == 1) ? hv1.y : (u == 2) ? hv1.z : hv1.w;
                float xe0 = (u == 0) ? xv0.x : (u == 1) ? xv0.y : (u == 2) ? xv0.z : xv0.w;
                float xe1 = (u == 0) ? xv1.x : (u == 1) ? xv1.y : (u == 2) ? xv1.z : xv1.w;
                acc0 += xe0 * wxv + he0 * whv;
                acc1 += xe1 * wxv + he1 * whv;
            }
        }

        float n0 = tanhf(acc0);
        float n1 = tanhf(acc1);
        __syncthreads();
        h0[j] = n0;
        h1[j] = n1;
        __syncthreads();
    }

    out[(size_t)b0 * HID + j] = h0[j];
    out[(size_t)b1 * HID + j] = h1[j];
}

// ---------------------------------------------------------------------------
extern "C" void kernel_launch(void* const* d_in, const int* in_sizes, int n_in,
                              void* d_out, int out_size, void* d_ws, size_t ws_size,
                              hipStream_t stream)
{
    const float* x    = (const float*)d_in[0];  // (128, 1024, 512)
    const float* Wx   = (const float*)d_in[1];  // (512, 512)
    const float* Wh   = (const float*)d_in[2];  // (512, 512)
    const float* bias = (const float*)d_in[3];  // (512,)
    float* out = (float*)d_out;                 // (128, 512)

    const size_t flagsBytes = (size_t)NG * FLAG_STRIDE * 4;              // 2 KB
    const size_t hxBytes    = 2ull * NG * RPB * HID * sizeof(float);     // 512 KB
    const size_t stepBytes  = (size_t)BATCH * HID * sizeof(float);       // 256 KB
    const size_t fixed      = flagsBytes + hxBytes;

    size_t xpCapSteps = (ws_size > fixed) ? (ws_size - fixed) / stepBytes : 0;

    if (xpCapSteps >= 1) {
        unsigned int* flags = (unsigned int*)d_ws;
        float* hx           = (float*)((char*)d_ws + flagsBytes);
        float* xp           = (float*)((char*)d_ws + fixed);

        init_ws<<<(INIT_WORDS + 255) / 256, 256, 0, stream>>>((unsigned int*)d_ws);

        int chunk = (int)((xpCapSteps < (size_t)SEQ) ? xpCapSteps : (size_t)SEQ);
        int s0 = 0;
        while (s0 < SEQ) {
            int steps = (SEQ - s0 < chunk) ? (SEQ - s0) : chunk;
            dim3 ggrid((unsigned)(steps * BATCH / 64), HID / 64);
            xp_gemm<<<ggrid, 256, 0, stream>>>(x, Wx, bias, xp, s0);
            recur_kernel<<<NG * NC, 512, 0, stream>>>(xp, Wh, out, flags, hx,
                                                      s0, steps);
            s0 += steps;
        }
    } else {
        fused_kernel<<<BATCH / 2, HID, 0, stream>>>(x, Wx, Wh, bias, out);
    }
}